// Round 7
// baseline (260.113 us; speedup 1.0000x reference)
//
#include <hip/hip_runtime.h>

#define EPS 1e-6f

constexpr int N_ = 8;
constexpr int H_ = 720;
constexpr int W_ = 1280;
constexpr int HW = H_ * W_;
constexpr int NPIX = N_ * HW;        // 7,372,800

// Tiling for the privatized splat (unchanged from R6's passing config).
// Confirmed model (R4/R5/R6): ds_add_u64 retires ~1.2-1.4 cyc/lane-op/CU,
// occupancy-independent (fire-and-forget). LDS window: u64 fixed-point
// {img_q26:32 | one_q26:32}, 120x80 tile, R=16 halo -> 152x112 = 17024
// cells, 136 KB LDS, 1 block/CU, 768 blocks = 3 exact GPU rounds.
//
// R7 restructure: NO ws, NO gather. R6 counters showed the ws round-trip
// is pure HBM traffic (WRITE_SIZE == ws size, 107 MB; gather re-fetches it
// plus 118 MB of out-plane r/w). The u64 pack makes both planes one
// addressable cell -> dump the LDS window DIRECTLY into a global u64
// accumulator image via global_atomic_add_u64 (native, fire-and-forget).
// The out-of-halo fallback adds the same packed quantity to the same
// accumulator (unified representation, no pre-zeroed out planes needed).
// finalize decodes + divides.
//
// Fixed-point safety (R3 fail at q20 -> R6 pass at q26, absmax 0.0078):
//  - quantum 2^-26; output sensitivity ~1/EPS -> absmax ~0.008-0.016.
//  - overflow: each ww < 0.41 (s >= 2.43), fields carry only past ~156
//    contributors/cell; contributors ~ Poisson(4). P ~ 0 globally.
constexpr int TH = 120;              // tile rows   (720 = 6*120, exact)
constexpr int TW = 80;               // tile cols   (1280 = 16*80, exact)
constexpr int R_ = 16;               // halo = 2 sigma of the sigma=8 flow
constexpr int LH = TH + 2 * R_;      // 152
constexpr int LW = TW + 2 * R_;      // 112
constexpr int LSZ = LH * LW;         // 17024 positions
constexpr int TILES_H = H_ / TH;     // 6
constexpr int TILES_W = W_ / TW;     // 16
constexpr int TILES_PER_IMG = TILES_H * TILES_W;        // 96

#define QSCALE 67108864.0f           // 2^26
#define QINV   (1.0f / 67108864.0f)

// Native f32 atomic add (global_atomic_add_f32) for the no-ws fallback path.
__device__ __forceinline__ void atomic_fadd(float* p, float v) {
    unsafeAtomicAdd(p, v);
}

// ---------------------------------------------------------------------------
// Phase A: per-tile privatized splat -> direct global packed accumulation.
// One block = one 120x80 source tile. LDS: one u64 plane for the 152x112
// halo'd window (4 x ds_add_u64 per pixel, the proven DS floor). Dump:
// one global_atomic_add_u64 per nonzero in-image window cell (no decode -
// the packed representation IS the global accumulator format).
// ---------------------------------------------------------------------------
__global__ __launch_bounds__(512) void splat_tiled_kernel(
        const float* __restrict__ img,
        const float* __restrict__ counts,
        const float* __restrict__ flo,
        unsigned long long* __restrict__ acc) {   // NPIX packed cells (zeroed)
    __shared__ __align__(16) unsigned long long s_acc[LSZ];   // 136,192 B

    int bt = blockIdx.x;                 // global tile id over all 8 images
    int tc = bt % TILES_W;
    int t2 = bt / TILES_W;
    int tr = t2 % TILES_H;
    int n  = t2 / TILES_H;
    int row0 = tr * TH;
    int col0 = tc * TW;
    int tid = threadIdx.x;

    // zero LDS (vectorized, conflict-free): 8512 float4
    {
        float4 z = make_float4(0.f, 0.f, 0.f, 0.f);
        float4* z0 = (float4*)s_acc;
        for (int i = tid; i < LSZ / 2; i += 512) z0[i] = z;
    }
    __syncthreads();

    int nbase = n * HW;
    int fbase_n = n * 2 * HW;

    for (int p = tid; p < TH * TW; p += 512) {
        int r = p / TW;
        int c = p % TW;
        int h = row0 + r;
        int w = col0 + c;
        int idx = nbase + h * W_ + w;

        float iv = img[idx];
        float cv = counts[idx];
        int fo = fbase_n + h * W_ + w;
        float y = flo[fo];                 // channel 0 shifts W axis
        float x = flo[fo + HW];            // channel 1 shifts H axis

        float x1 = floorf(x);
        float y1 = floorf(y);
        float fx = x - x1;
        float fy = y - y1;
        float gx = 1.0f - fx;
        float gy = 1.0f - fy;
        float ex1 = __expf(-fx * fx);
        float ex2 = __expf(-gx * gx);
        float ey1 = __expf(-fy * fy);
        float ey2 = __expf(-gy * gy);

        float s = (ex1 + ex2) * (ey1 + ey2);
        float inv = cv / s;

        int ix1 = (int)x1 + h;
        int iy1 = (int)y1 + w;

        int ixr[2] = {ix1, ix1 + 1};
        int iyc[2] = {iy1, iy1 + 1};
        float wx[2] = {ex1, ex2};
        float wy[2] = {ey1, ey2};

        #pragma unroll
        for (int a = 0; a < 2; ++a) {
            #pragma unroll
            for (int b = 0; b < 2; ++b) {
                float ww = wx[a] * wy[b] * inv;
                float wi = iv * ww;
                unsigned qi = (unsigned)(wi * QSCALE + 0.5f);
                unsigned qw = (unsigned)(ww * QSCALE + 0.5f);
                unsigned long long pk =
                    ((unsigned long long)qi << 32) | (unsigned long long)qw;
                int lh = ixr[a] - row0 + R_;
                int lw = iyc[b] - col0 + R_;
                if ((unsigned)lh < (unsigned)LH && (unsigned)lw < (unsigned)LW) {
                    atomicAdd(&s_acc[lh * LW + lw], pk);     // ds_add_u64
                } else if ((unsigned)ixr[a] < (unsigned)H_ &&
                           (unsigned)iyc[b] < (unsigned)W_) {
                    atomicAdd(&acc[nbase + ixr[a] * W_ + iyc[b]], pk); // rare
                }
            }
        }
    }
    __syncthreads();

    // dump: LDS window -> global packed accumulator, one u64 atomic per
    // nonzero in-image cell. No decode; fire-and-forget; overlaps with the
    // next block-round's LDS phase on the same CU.
    for (int i = tid; i < LSZ; i += 512) {
        unsigned long long v = s_acc[i];
        if (v == 0ull) continue;
        int lh = i / LW;
        int lw = i - lh * LW;
        int gr = row0 - R_ + lh;
        int gc = col0 - R_ + lw;
        if ((unsigned)gr < (unsigned)H_ && (unsigned)gc < (unsigned)W_)
            atomicAdd(&acc[nbase + gr * W_ + gc], v);
    }
}

// ---------------------------------------------------------------------------
// Phase B: finalize. Decode packed q26 accumulator -> out0 = img/(one+eps),
// out1 = one. 4 cells/thread: 32 B in, 2x16 B out, fully coalesced.
// ---------------------------------------------------------------------------
__global__ __launch_bounds__(256) void finalize_packed_kernel(
        const unsigned long long* __restrict__ acc,
        float* __restrict__ out0,
        float* __restrict__ out1) {
    int i4 = (blockIdx.x * 256 + threadIdx.x) * 4;
    if (i4 >= NPIX) return;

    const ulonglong2* a2 = (const ulonglong2*)(acc + i4);
    ulonglong2 p0 = a2[0];
    ulonglong2 p1 = a2[1];

    float4 fi, fo;
    fi.x = (float)(unsigned)(p0.x >> 32) * QINV;
    fo.x = (float)(unsigned)(p0.x & 0xffffffffull) * QINV;
    fi.y = (float)(unsigned)(p0.y >> 32) * QINV;
    fo.y = (float)(unsigned)(p0.y & 0xffffffffull) * QINV;
    fi.z = (float)(unsigned)(p1.x >> 32) * QINV;
    fo.z = (float)(unsigned)(p1.x & 0xffffffffull) * QINV;
    fi.w = (float)(unsigned)(p1.y >> 32) * QINV;
    fo.w = (float)(unsigned)(p1.y & 0xffffffffull) * QINV;

    float4 r;
    r.x = fi.x / (fo.x + EPS);
    r.y = fi.y / (fo.y + EPS);
    r.z = fi.z / (fo.z + EPS);
    r.w = fi.w / (fo.w + EPS);
    *(float4*)(out0 + i4) = r;
    *(float4*)(out1 + i4) = fo;
}

// ---------------------------------------------------------------------------
// Fallback path (ws smaller than the packed accumulator): direct f32
// atomics into the out planes + divide.
// ---------------------------------------------------------------------------
__global__ void splat_atomic_kernel(const float* __restrict__ img,
                                    const float* __restrict__ counts,
                                    const float* __restrict__ flo,
                                    float* __restrict__ acc_img,
                                    float* __restrict__ acc_one) {
    int idx = blockIdx.x * blockDim.x + threadIdx.x;
    if (idx >= NPIX) return;
    int w = idx % W_;
    int t = idx / W_;
    int h = t % H_;
    int n = t / H_;

    float iv = img[idx];
    float cv = counts[idx];
    int fbase = ((n * 2) * H_ + h) * W_ + w;
    float y = flo[fbase];
    float x = flo[fbase + HW];

    float x1 = floorf(x);
    float y1 = floorf(y);
    float fx = x - x1, fy = y - y1;
    float gx = 1.0f - fx, gy = 1.0f - fy;
    float ex1 = __expf(-fx * fx), ex2 = __expf(-gx * gx);
    float ey1 = __expf(-fy * fy), ey2 = __expf(-gy * gy);
    float s = (ex1 + ex2) * (ey1 + ey2);
    float inv = cv / s;

    int ix1 = (int)x1 + h, ix2 = ix1 + 1;
    int iy1 = (int)y1 + w, iy2 = iy1 + 1;
    int nbase = n * HW;
    if ((unsigned)ix1 < (unsigned)H_ && (unsigned)iy1 < (unsigned)W_) {
        int o = nbase + ix1 * W_ + iy1; float ww = ex1 * ey1 * inv;
        atomic_fadd(acc_img + o, iv * ww); atomic_fadd(acc_one + o, ww);
    }
    if ((unsigned)ix1 < (unsigned)H_ && (unsigned)iy2 < (unsigned)W_) {
        int o = nbase + ix1 * W_ + iy2; float ww = ex1 * ey2 * inv;
        atomic_fadd(acc_img + o, iv * ww); atomic_fadd(acc_one + o, ww);
    }
    if ((unsigned)ix2 < (unsigned)H_ && (unsigned)iy1 < (unsigned)W_) {
        int o = nbase + ix2 * W_ + iy1; float ww = ex2 * ey1 * inv;
        atomic_fadd(acc_img + o, iv * ww); atomic_fadd(acc_one + o, ww);
    }
    if ((unsigned)ix2 < (unsigned)H_ && (unsigned)iy2 < (unsigned)W_) {
        int o = nbase + ix2 * W_ + iy2; float ww = ex2 * ey2 * inv;
        atomic_fadd(acc_img + o, iv * ww); atomic_fadd(acc_one + o, ww);
    }
}

__global__ void finalize_kernel(float* __restrict__ out0,
                                const float* __restrict__ out1) {
    int idx = blockIdx.x * blockDim.x + threadIdx.x;
    if (idx >= NPIX) return;
    out0[idx] = out0[idx] / (out1[idx] + EPS);
}

extern "C" void kernel_launch(void* const* d_in, const int* in_sizes, int n_in,
                              void* d_out, int out_size, void* d_ws, size_t ws_size,
                              hipStream_t stream) {
    const float* img    = (const float*)d_in[0];
    const float* counts = (const float*)d_in[1];
    const float* flo    = (const float*)d_in[2];

    float* out0 = (float*)d_out;
    float* out1 = out0 + NPIX;

    if (ws_size >= (size_t)NPIX * sizeof(unsigned long long)) {
        // Packed path: zero the u64 accumulator (59 MB), splat directly
        // into it, then decode+divide. No out-plane memset needed -
        // finalize writes every output cell.
        unsigned long long* acc = (unsigned long long*)d_ws;
        hipMemsetAsync(acc, 0, (size_t)NPIX * sizeof(unsigned long long),
                       stream);
        splat_tiled_kernel<<<N_ * TILES_PER_IMG, 512, 0, stream>>>(
            img, counts, flo, acc);
        finalize_packed_kernel<<<NPIX / 4 / 256, 256, 0, stream>>>(
            acc, out0, out1);
    } else {
        hipMemsetAsync(d_out, 0, (size_t)2 * NPIX * sizeof(float), stream);
        const int threads = 256;
        const int blocks = (NPIX + threads - 1) / threads;
        splat_atomic_kernel<<<blocks, threads, 0, stream>>>(img, counts, flo,
                                                            out0, out1);
        finalize_kernel<<<blocks, threads, 0, stream>>>(out0, out1);
    }
}

// Round 8
// 229.768 us; speedup vs baseline: 1.1321x; 1.1321x over previous
//
#include <hip/hip_runtime.h>

#define EPS 1e-6f

constexpr int N_ = 8;
constexpr int H_ = 720;
constexpr int W_ = 1280;
constexpr int HW = H_ * W_;
constexpr int NPIX = N_ * HW;        // 7,372,800

// Tiling for the privatized splat.
// Confirmed model (R4-R7): LDS ds_add_u64 serializes per LANE at ~1.3
// cyc/lane-RMW when the pipe is fed; splat time = lane-RMW count /
// (256 CU x feed-fraction). R6 (1 block/CU, 136 KB window) measured 1.94
// cyc/lane-RMW -> ~33% of time the DS pipe sat idle (zero/stage/dump
// phases of the single resident block). R8: shrink the window to
// 79,872 B -> TWO blocks/CU so one block's atomic phase overlaps the
// other's staging/dump. R7's direct-global-atomic dump REGRESSED
// (device-scope u64 RMWs serialize at the memory-side coherent point);
// plain ws stores + L3-resident gather is the proven structure.
constexpr int TH = 72;               // tile rows   (720 = 10*72, exact)
constexpr int TW = 64;               // tile cols   (1280 = 20*64, exact)
constexpr int R_ = 16;               // halo = 2 sigma of the sigma=8 flow
constexpr int LH = TH + 2 * R_;      // 104
constexpr int LW = TW + 2 * R_;      // 96
constexpr int LSZ = LH * LW;         // 9984 positions
constexpr int TILES_H = H_ / TH;     // 10
constexpr int TILES_W = W_ / TW;     // 20
constexpr int TILES_PER_IMG = TILES_H * TILES_W;        // 200
constexpr size_t WS_PER_IMG = (size_t)TILES_PER_IMG * LSZ * 2 * sizeof(float); // ~15.2 MiB
// 8 images -> ~122 MiB ws: whole batch in ONE chunk, Infinity-Cache resident.

// Fixed-point pack {img_q26:32 | one_q26:32} (R6-verified: absmax 0.0078,
// 8x under threshold; overflow needs >=64 contributors/cell vs Poisson(4)).
#define QSCALE 67108864.0f           // 2^26
#define QINV   (1.0f / 67108864.0f)

// Native f32 atomic add (global_atomic_add_f32) for the rare fallback.
__device__ __forceinline__ void atomic_fadd(float* p, float v) {
    unsafeAtomicAdd(p, v);
}

// ---------------------------------------------------------------------------
// Phase A: per-tile privatized splat. One block = one 72x64 source tile.
// LDS: one u64 plane {img_q26|one_q26} for the 104x96 halo'd window
// (79,872 B -> 2 blocks/CU). 4 x ds_add_u64 per pixel. Out-of-halo
// (2-sigma tail, ~0.4% of corners) -> exact f32 global atomics into the
// output planes (pre-zeroed, read by gather as initial values).
// ---------------------------------------------------------------------------
__global__ __launch_bounds__(512) void splat_tiled_kernel(
        const float* __restrict__ img,
        const float* __restrict__ counts,
        const float* __restrict__ flo,
        float* __restrict__ ws,          // ni * 200 * LSZ * 2 floats
        float* __restrict__ fb_img,      // fallback accumulators = d_out planes
        float* __restrict__ fb_one,
        int n0) {
    __shared__ __align__(16) unsigned long long s_acc[LSZ];   // 79,872 B

    int bt = blockIdx.x;                 // chunk-local tile id
    int tc = bt % TILES_W;
    int t2 = bt / TILES_W;
    int tr = t2 % TILES_H;
    int n  = n0 + t2 / TILES_H;
    int row0 = tr * TH;
    int col0 = tc * TW;
    int tid = threadIdx.x;

    // zero LDS (vectorized, conflict-free): 4992 float4
    {
        float4 z = make_float4(0.f, 0.f, 0.f, 0.f);
        float4* z0 = (float4*)s_acc;
        for (int i = tid; i < LSZ / 2; i += 512) z0[i] = z;
    }
    __syncthreads();

    int nbase = n * HW;
    int fbase_n = n * 2 * HW;

    // TH*TW = 4608 = 9 * 512: exactly 9 iterations, no tail; TW=64 -> bit ops.
    for (int p = tid; p < TH * TW; p += 512) {
        int r = p >> 6;
        int c = p & 63;
        int h = row0 + r;
        int w = col0 + c;
        int idx = nbase + h * W_ + w;

        float iv = img[idx];
        float cv = counts[idx];
        int fo = fbase_n + h * W_ + w;
        float y = flo[fo];                 // channel 0 shifts W axis
        float x = flo[fo + HW];            // channel 1 shifts H axis

        float x1 = floorf(x);
        float y1 = floorf(y);
        float fx = x - x1;
        float fy = y - y1;
        float gx = 1.0f - fx;
        float gy = 1.0f - fy;
        float ex1 = __expf(-fx * fx);
        float ex2 = __expf(-gx * gx);
        float ey1 = __expf(-fy * fy);
        float ey2 = __expf(-gy * gy);

        float s = (ex1 + ex2) * (ey1 + ey2);
        float inv = cv / s;

        int ix1 = (int)x1 + h;
        int iy1 = (int)y1 + w;

        int ixr[2] = {ix1, ix1 + 1};
        int iyc[2] = {iy1, iy1 + 1};
        float wx[2] = {ex1, ex2};
        float wy[2] = {ey1, ey2};

        #pragma unroll
        for (int a = 0; a < 2; ++a) {
            #pragma unroll
            for (int b = 0; b < 2; ++b) {
                float ww = wx[a] * wy[b] * inv;
                float wi = iv * ww;
                int lh = ixr[a] - row0 + R_;
                int lw = iyc[b] - col0 + R_;
                if ((unsigned)lh < (unsigned)LH && (unsigned)lw < (unsigned)LW) {
                    unsigned qi = (unsigned)(wi * QSCALE + 0.5f);
                    unsigned qw = (unsigned)(ww * QSCALE + 0.5f);
                    atomicAdd(&s_acc[lh * LW + lw],
                              ((unsigned long long)qi << 32) |
                               (unsigned long long)qw);      // ds_add_u64
                } else if ((unsigned)ixr[a] < (unsigned)H_ &&
                           (unsigned)iyc[b] < (unsigned)W_) {
                    int o = nbase + ixr[a] * W_ + iyc[b];
                    atomic_fadd(fb_img + o, wi);   // exact f32, rare tail
                    atomic_fadd(fb_one + o, ww);
                }
            }
        }
    }
    __syncthreads();

    // private, coalesced dump: decode fixed point -> {img,one} f32 pairs,
    // 2 cells (one float4) per store. ws layout unchanged for gather.
    float4* wsb = (float4*)(ws + (size_t)bt * LSZ * 2);
    for (int i = tid; i < LSZ / 2; i += 512) {
        unsigned long long v0 = s_acc[2 * i];
        unsigned long long v1 = s_acc[2 * i + 1];
        float4 o4;
        o4.x = (float)(unsigned)(v0 >> 32) * QINV;
        o4.y = (float)(unsigned)(v0 & 0xffffffffull) * QINV;
        o4.z = (float)(unsigned)(v1 >> 32) * QINV;
        o4.w = (float)(unsigned)(v1 & 0xffffffffull) * QINV;
        wsb[i] = o4;
    }
}

// ---------------------------------------------------------------------------
// Phase B: gather, 4 pixels per thread via float4. Tile-boundary thresholds
// (R_=16, TW-R_=48, TW=64) are multiples of 4, so an aligned 4-pixel quad
// provably shares one (tr,tc) tile set -> no intra-quad divergence; each
// tile contribution is two float4 loads. ws (~122 MiB) is L3-resident.
// ---------------------------------------------------------------------------
__global__ __launch_bounds__(256) void gather_kernel(
        const float* __restrict__ ws,
        float* __restrict__ out0,
        float* __restrict__ out1,
        int n0, int npix_chunk) {
    int pidx = (blockIdx.x * 256 + threadIdx.x) * 4;
    if (pidx >= npix_chunk) return;
    int w0 = pidx % W_;               // multiple of 4
    int t = pidx / W_;
    int h = t % H_;                   // uniform across each wave (256 | W_)
    int nl = t / H_;                  // chunk-local image index

    int gidx = (n0 + nl) * HW + h * W_ + w0;

    float4 fi = *(const float4*)(out0 + gidx);   // fallback accum (usually 0)
    float4 fo = *(const float4*)(out1 + gidx);

    int tr_lo = (h >= R_) ? (h - R_) / TH : 0;
    int tr_hi = (h + R_) / TH; if (tr_hi > TILES_H - 1) tr_hi = TILES_H - 1;
    int tc_lo = (w0 >= R_) ? (w0 - R_) / TW : 0;
    int tc_hi = (w0 + 3 + R_) / TW; if (tc_hi > TILES_W - 1) tc_hi = TILES_W - 1;

    for (int tr = tr_lo; tr <= tr_hi; ++tr) {
        int lh = h - tr * TH + R_;
        for (int tc = tc_lo; tc <= tc_hi; ++tc) {
            int lw0 = w0 - tc * TW + R_;
            const float* bp = ws
                + ((size_t)((nl * TILES_H + tr) * TILES_W + tc)) * (LSZ * 2)
                + (size_t)(lh * LW + lw0) * 2;
            float4 a = *(const float4*)bp;        // cells w0, w0+1
            float4 b = *(const float4*)(bp + 4);  // cells w0+2, w0+3
            fi.x += a.x; fo.x += a.y;
            fi.y += a.z; fo.y += a.w;
            fi.z += b.x; fo.z += b.y;
            fi.w += b.z; fo.w += b.w;
        }
    }
    float4 r;
    r.x = fi.x / (fo.x + EPS);
    r.y = fi.y / (fo.y + EPS);
    r.z = fi.z / (fo.z + EPS);
    r.w = fi.w / (fo.w + EPS);
    *(float4*)(out0 + gidx) = r;
    *(float4*)(out1 + gidx) = fo;
}

// ---------------------------------------------------------------------------
// Fallback path (ws smaller than one image's tiles): direct-atomic version.
// ---------------------------------------------------------------------------
__global__ void splat_atomic_kernel(const float* __restrict__ img,
                                    const float* __restrict__ counts,
                                    const float* __restrict__ flo,
                                    float* __restrict__ acc_img,
                                    float* __restrict__ acc_one) {
    int idx = blockIdx.x * blockDim.x + threadIdx.x;
    if (idx >= NPIX) return;
    int w = idx % W_;
    int t = idx / W_;
    int h = t % H_;
    int n = t / H_;

    float iv = img[idx];
    float cv = counts[idx];
    int fbase = ((n * 2) * H_ + h) * W_ + w;
    float y = flo[fbase];
    float x = flo[fbase + HW];

    float x1 = floorf(x);
    float y1 = floorf(y);
    float fx = x - x1, fy = y - y1;
    float gx = 1.0f - fx, gy = 1.0f - fy;
    float ex1 = __expf(-fx * fx), ex2 = __expf(-gx * gx);
    float ey1 = __expf(-fy * fy), ey2 = __expf(-gy * gy);
    float s = (ex1 + ex2) * (ey1 + ey2);
    float inv = cv / s;

    int ix1 = (int)x1 + h, ix2 = ix1 + 1;
    int iy1 = (int)y1 + w, iy2 = iy1 + 1;
    int nbase = n * HW;
    if ((unsigned)ix1 < (unsigned)H_ && (unsigned)iy1 < (unsigned)W_) {
        int o = nbase + ix1 * W_ + iy1; float ww = ex1 * ey1 * inv;
        atomic_fadd(acc_img + o, iv * ww); atomic_fadd(acc_one + o, ww);
    }
    if ((unsigned)ix1 < (unsigned)H_ && (unsigned)iy2 < (unsigned)W_) {
        int o = nbase + ix1 * W_ + iy2; float ww = ex1 * ey2 * inv;
        atomic_fadd(acc_img + o, iv * ww); atomic_fadd(acc_one + o, ww);
    }
    if ((unsigned)ix2 < (unsigned)H_ && (unsigned)iy1 < (unsigned)W_) {
        int o = nbase + ix2 * W_ + iy1; float ww = ex2 * ey1 * inv;
        atomic_fadd(acc_img + o, iv * ww); atomic_fadd(acc_one + o, ww);
    }
    if ((unsigned)ix2 < (unsigned)H_ && (unsigned)iy2 < (unsigned)W_) {
        int o = nbase + ix2 * W_ + iy2; float ww = ex2 * ey2 * inv;
        atomic_fadd(acc_img + o, iv * ww); atomic_fadd(acc_one + o, ww);
    }
}

__global__ void finalize_kernel(float* __restrict__ out0,
                                const float* __restrict__ out1) {
    int idx = blockIdx.x * blockDim.x + threadIdx.x;
    if (idx >= NPIX) return;
    out0[idx] = out0[idx] / (out1[idx] + EPS);
}

extern "C" void kernel_launch(void* const* d_in, const int* in_sizes, int n_in,
                              void* d_out, int out_size, void* d_ws, size_t ws_size,
                              hipStream_t stream) {
    const float* img    = (const float*)d_in[0];
    const float* counts = (const float*)d_in[1];
    const float* flo    = (const float*)d_in[2];

    float* out0 = (float*)d_out;
    float* out1 = out0 + NPIX;

    // d_out is re-poisoned before every call; both planes double as
    // fallback atomic accumulators -> zero them.
    hipMemsetAsync(d_out, 0, (size_t)2 * NPIX * sizeof(float), stream);

    // ws ~15.2 MiB/img -> whole 8-image batch in one chunk (~122 MiB,
    // Infinity-Cache resident between splat and gather).
    int ipc = (int)(ws_size / WS_PER_IMG);
    if (ipc > N_) ipc = N_;

    if (ipc >= 1) {
        float* ws = (float*)d_ws;  // one chunk region, reused (stream-serialized)
        for (int n0 = 0; n0 < N_; n0 += ipc) {
            int ni = (n0 + ipc <= N_) ? ipc : (N_ - n0);
            splat_tiled_kernel<<<ni * TILES_PER_IMG, 512, 0, stream>>>(
                img, counts, flo, ws, out0, out1, n0);
            int npix_chunk = ni * HW;
            gather_kernel<<<(npix_chunk / 4 + 255) / 256, 256, 0, stream>>>(
                ws, out0, out1, n0, npix_chunk);
        }
    } else {
        const int threads = 256;
        const int blocks = (NPIX + threads - 1) / threads;
        splat_atomic_kernel<<<blocks, threads, 0, stream>>>(img, counts, flo,
                                                            out0, out1);
        finalize_kernel<<<blocks, threads, 0, stream>>>(out0, out1);
    }
}

// Round 9
// 207.508 us; speedup vs baseline: 1.2535x; 1.1073x over previous
//
#include <hip/hip_runtime.h>
#include <hip/hip_fp16.h>

#define EPS 1e-6f

constexpr int N_ = 8;
constexpr int H_ = 720;
constexpr int W_ = 1280;
constexpr int HW = H_ * W_;
constexpr int NPIX = N_ * HW;        // 7,372,800

// Tiling for the privatized splat (R8-verified config: 82 us splat).
// Confirmed model (R4-R8): LDS ds_add_u64 serializes per LANE at ~1.3-1.7
// cyc/lane-RMW; 2 blocks/CU (79,872 B window) keeps the DS pipe ~80% fed.
// R9 change: ws cells stored as packed 2xf16 (4 B/cell, value pre-scaled
// by 2^10 to clear f16 denormals) -> gather reads ONE uint4 per
// tile-contribution per 4-pixel quad (was two float4), ws 122->61 MB,
// dump writes halve. LDS accumulation stays exact u64 q26; only the final
// per-tile sums round to f16 once (rel err 2^-11, scale-free in the
// out0 ratio; out1 abs err ~o_max*5e-4 ~ 0.004 << 0.06 threshold).
constexpr int TH = 72;               // tile rows   (720 = 10*72, exact)
constexpr int TW = 64;               // tile cols   (1280 = 20*64, exact)
constexpr int R_ = 16;               // halo = 2 sigma of the sigma=8 flow
constexpr int LH = TH + 2 * R_;      // 104
constexpr int LW = TW + 2 * R_;      // 96
constexpr int LSZ = LH * LW;         // 9984 positions
constexpr int TILES_H = H_ / TH;     // 10
constexpr int TILES_W = W_ / TW;     // 20
constexpr int TILES_PER_IMG = TILES_H * TILES_W;        // 200
constexpr size_t WS_PER_IMG = (size_t)TILES_PER_IMG * LSZ * 4; // ~8 MiB (u32 cells)
// 8 images -> ~64 MiB ws: whole batch one chunk, L3-resident with out planes.

// Fixed-point LDS pack {img_q26:32 | one_q26:32} (R6/R8-verified:
// absmax 0.0078; overflow needs >=64 contributors/cell vs Poisson(4)).
#define QSCALE 67108864.0f           // 2^26
// q26 int -> f16-stored value (true * 2^10): multiply by 2^-16.
#define QI16   (1.0f / 65536.0f)
// gather unscale: stored -> true
#define SINV   (1.0f / 1024.0f)

// Native f32 atomic add (global_atomic_add_f32) for the rare fallback.
__device__ __forceinline__ void atomic_fadd(float* p, float v) {
    unsafeAtomicAdd(p, v);
}

__device__ __forceinline__ unsigned pack_cell(unsigned long long v) {
    float im = (float)(unsigned)(v >> 32) * QI16;          // true*2^10
    float on = (float)(unsigned)(v & 0xffffffffull) * QI16;
    unsigned hi = (unsigned)__half_as_ushort(__float2half(im));
    unsigned ho = (unsigned)__half_as_ushort(__float2half(on));
    return hi | (ho << 16);          // low = img, high = one
}

// ---------------------------------------------------------------------------
// Phase A: per-tile privatized splat. One block = one 72x64 source tile.
// LDS: one u64 plane {img_q26|one_q26} for the 104x96 halo'd window
// (79,872 B -> 2 blocks/CU). 4 x ds_add_u64 per pixel. Out-of-halo
// (2-sigma tail, ~0.4% of corners) -> exact f32 global atomics into the
// pre-zeroed output planes (read by gather as initial values).
// ---------------------------------------------------------------------------
__global__ __launch_bounds__(512) void splat_tiled_kernel(
        const float* __restrict__ img,
        const float* __restrict__ counts,
        const float* __restrict__ flo,
        unsigned* __restrict__ ws,       // ni * 200 * LSZ packed-h2 cells
        float* __restrict__ fb_img,      // fallback accumulators = d_out planes
        float* __restrict__ fb_one,
        int n0) {
    __shared__ __align__(16) unsigned long long s_acc[LSZ];   // 79,872 B

    int bt = blockIdx.x;                 // chunk-local tile id
    int tc = bt % TILES_W;
    int t2 = bt / TILES_W;
    int tr = t2 % TILES_H;
    int n  = n0 + t2 / TILES_H;
    int row0 = tr * TH;
    int col0 = tc * TW;
    int tid = threadIdx.x;

    // zero LDS (vectorized, conflict-free): 4992 float4
    {
        float4 z = make_float4(0.f, 0.f, 0.f, 0.f);
        float4* z0 = (float4*)s_acc;
        for (int i = tid; i < LSZ / 2; i += 512) z0[i] = z;
    }
    __syncthreads();

    int nbase = n * HW;
    int fbase_n = n * 2 * HW;

    // TH*TW = 4608 = 9 * 512: exactly 9 iterations, no tail; TW=64 -> bit ops.
    for (int p = tid; p < TH * TW; p += 512) {
        int r = p >> 6;
        int c = p & 63;
        int h = row0 + r;
        int w = col0 + c;
        int idx = nbase + h * W_ + w;

        float iv = img[idx];
        float cv = counts[idx];
        int fo = fbase_n + h * W_ + w;
        float y = flo[fo];                 // channel 0 shifts W axis
        float x = flo[fo + HW];            // channel 1 shifts H axis

        float x1 = floorf(x);
        float y1 = floorf(y);
        float fx = x - x1;
        float fy = y - y1;
        float gx = 1.0f - fx;
        float gy = 1.0f - fy;
        float ex1 = __expf(-fx * fx);
        float ex2 = __expf(-gx * gx);
        float ey1 = __expf(-fy * fy);
        float ey2 = __expf(-gy * gy);

        float s = (ex1 + ex2) * (ey1 + ey2);
        float inv = cv / s;

        int ix1 = (int)x1 + h;
        int iy1 = (int)y1 + w;

        int ixr[2] = {ix1, ix1 + 1};
        int iyc[2] = {iy1, iy1 + 1};
        float wx[2] = {ex1, ex2};
        float wy[2] = {ey1, ey2};

        #pragma unroll
        for (int a = 0; a < 2; ++a) {
            #pragma unroll
            for (int b = 0; b < 2; ++b) {
                float ww = wx[a] * wy[b] * inv;
                float wi = iv * ww;
                int lh = ixr[a] - row0 + R_;
                int lw = iyc[b] - col0 + R_;
                if ((unsigned)lh < (unsigned)LH && (unsigned)lw < (unsigned)LW) {
                    unsigned qi = (unsigned)(wi * QSCALE + 0.5f);
                    unsigned qw = (unsigned)(ww * QSCALE + 0.5f);
                    atomicAdd(&s_acc[lh * LW + lw],
                              ((unsigned long long)qi << 32) |
                               (unsigned long long)qw);      // ds_add_u64
                } else if ((unsigned)ixr[a] < (unsigned)H_ &&
                           (unsigned)iyc[b] < (unsigned)W_) {
                    int o = nbase + ixr[a] * W_ + iyc[b];
                    atomic_fadd(fb_img + o, wi);   // exact f32, rare tail
                    atomic_fadd(fb_one + o, ww);
                }
            }
        }
    }
    __syncthreads();

    // private, coalesced dump: decode q26 -> packed f16 pair per cell,
    // 4 cells (one uint4) per store. LSZ/4 = 2496 cells-groups.
    uint4* wsb = (uint4*)(ws + (size_t)bt * LSZ);
    for (int i = tid; i < LSZ / 4; i += 512) {
        uint4 o4;
        o4.x = pack_cell(s_acc[4 * i]);
        o4.y = pack_cell(s_acc[4 * i + 1]);
        o4.z = pack_cell(s_acc[4 * i + 2]);
        o4.w = pack_cell(s_acc[4 * i + 3]);
        wsb[i] = o4;
    }
}

// ---------------------------------------------------------------------------
// Phase B: gather, 4 pixels per thread. Tile-boundary thresholds (R_=16,
// TW-R_=48, TW=64) are multiples of 4, so an aligned 4-pixel quad shares
// one (tr,tc) tile set; each tile contribution is ONE uint4 load (4 packed
// cells). ws (~61 MiB) + out planes (59 MB) are L3-resident.
// ---------------------------------------------------------------------------
__global__ __launch_bounds__(256) void gather_kernel(
        const unsigned* __restrict__ ws,
        float* __restrict__ out0,
        float* __restrict__ out1,
        int n0, int npix_chunk) {
    int pidx = (blockIdx.x * 256 + threadIdx.x) * 4;
    if (pidx >= npix_chunk) return;
    int w0 = pidx % W_;               // multiple of 4
    int t = pidx / W_;
    int h = t % H_;                   // uniform across each wave (256 | W_)
    int nl = t / H_;                  // chunk-local image index

    int gidx = (n0 + nl) * HW + h * W_ + w0;

    float4 fi = *(const float4*)(out0 + gidx);   // fallback accum (usually 0)
    float4 fo = *(const float4*)(out1 + gidx);

    // scaled (x2^10) partial sums from ws
    float4 si = make_float4(0.f, 0.f, 0.f, 0.f);
    float4 so = make_float4(0.f, 0.f, 0.f, 0.f);

    int tr_lo = (h >= R_) ? (h - R_) / TH : 0;
    int tr_hi = (h + R_) / TH; if (tr_hi > TILES_H - 1) tr_hi = TILES_H - 1;
    int tc_lo = (w0 >= R_) ? (w0 - R_) / TW : 0;
    int tc_hi = (w0 + 3 + R_) / TW; if (tc_hi > TILES_W - 1) tc_hi = TILES_W - 1;

    for (int tr = tr_lo; tr <= tr_hi; ++tr) {
        int lh = h - tr * TH + R_;
        for (int tc = tc_lo; tc <= tc_hi; ++tc) {
            int lw0 = w0 - tc * TW + R_;          // multiple of 4
            const uint4 a = *(const uint4*)(ws
                + ((size_t)((nl * TILES_H + tr) * TILES_W + tc)) * LSZ
                + (size_t)(lh * LW + lw0));
            si.x += __half2float(__ushort_as_half((unsigned short)(a.x & 0xffff)));
            so.x += __half2float(__ushort_as_half((unsigned short)(a.x >> 16)));
            si.y += __half2float(__ushort_as_half((unsigned short)(a.y & 0xffff)));
            so.y += __half2float(__ushort_as_half((unsigned short)(a.y >> 16)));
            si.z += __half2float(__ushort_as_half((unsigned short)(a.z & 0xffff)));
            so.z += __half2float(__ushort_as_half((unsigned short)(a.z >> 16)));
            si.w += __half2float(__ushort_as_half((unsigned short)(a.w & 0xffff)));
            so.w += __half2float(__ushort_as_half((unsigned short)(a.w >> 16)));
        }
    }
    fi.x += si.x * SINV; fo.x += so.x * SINV;
    fi.y += si.y * SINV; fo.y += so.y * SINV;
    fi.z += si.z * SINV; fo.z += so.z * SINV;
    fi.w += si.w * SINV; fo.w += so.w * SINV;

    float4 r;
    r.x = fi.x / (fo.x + EPS);
    r.y = fi.y / (fo.y + EPS);
    r.z = fi.z / (fo.z + EPS);
    r.w = fi.w / (fo.w + EPS);
    *(float4*)(out0 + gidx) = r;
    *(float4*)(out1 + gidx) = fo;
}

// ---------------------------------------------------------------------------
// Fallback path (ws smaller than one image's tiles): direct-atomic version.
// ---------------------------------------------------------------------------
__global__ void splat_atomic_kernel(const float* __restrict__ img,
                                    const float* __restrict__ counts,
                                    const float* __restrict__ flo,
                                    float* __restrict__ acc_img,
                                    float* __restrict__ acc_one) {
    int idx = blockIdx.x * blockDim.x + threadIdx.x;
    if (idx >= NPIX) return;
    int w = idx % W_;
    int t = idx / W_;
    int h = t % H_;
    int n = t / H_;

    float iv = img[idx];
    float cv = counts[idx];
    int fbase = ((n * 2) * H_ + h) * W_ + w;
    float y = flo[fbase];
    float x = flo[fbase + HW];

    float x1 = floorf(x);
    float y1 = floorf(y);
    float fx = x - x1, fy = y - y1;
    float gx = 1.0f - fx, gy = 1.0f - fy;
    float ex1 = __expf(-fx * fx), ex2 = __expf(-gx * gx);
    float ey1 = __expf(-fy * fy), ey2 = __expf(-gy * gy);
    float s = (ex1 + ex2) * (ey1 + ey2);
    float inv = cv / s;

    int ix1 = (int)x1 + h, ix2 = ix1 + 1;
    int iy1 = (int)y1 + w, iy2 = iy1 + 1;
    int nbase = n * HW;
    if ((unsigned)ix1 < (unsigned)H_ && (unsigned)iy1 < (unsigned)W_) {
        int o = nbase + ix1 * W_ + iy1; float ww = ex1 * ey1 * inv;
        atomic_fadd(acc_img + o, iv * ww); atomic_fadd(acc_one + o, ww);
    }
    if ((unsigned)ix1 < (unsigned)H_ && (unsigned)iy2 < (unsigned)W_) {
        int o = nbase + ix1 * W_ + iy2; float ww = ex1 * ey2 * inv;
        atomic_fadd(acc_img + o, iv * ww); atomic_fadd(acc_one + o, ww);
    }
    if ((unsigned)ix2 < (unsigned)H_ && (unsigned)iy1 < (unsigned)W_) {
        int o = nbase + ix2 * W_ + iy1; float ww = ex2 * ey1 * inv;
        atomic_fadd(acc_img + o, iv * ww); atomic_fadd(acc_one + o, ww);
    }
    if ((unsigned)ix2 < (unsigned)H_ && (unsigned)iy2 < (unsigned)W_) {
        int o = nbase + ix2 * W_ + iy2; float ww = ex2 * ey2 * inv;
        atomic_fadd(acc_img + o, iv * ww); atomic_fadd(acc_one + o, ww);
    }
}

__global__ void finalize_kernel(float* __restrict__ out0,
                                const float* __restrict__ out1) {
    int idx = blockIdx.x * blockDim.x + threadIdx.x;
    if (idx >= NPIX) return;
    out0[idx] = out0[idx] / (out1[idx] + EPS);
}

extern "C" void kernel_launch(void* const* d_in, const int* in_sizes, int n_in,
                              void* d_out, int out_size, void* d_ws, size_t ws_size,
                              hipStream_t stream) {
    const float* img    = (const float*)d_in[0];
    const float* counts = (const float*)d_in[1];
    const float* flo    = (const float*)d_in[2];

    float* out0 = (float*)d_out;
    float* out1 = out0 + NPIX;

    // d_out is re-poisoned before every call; both planes double as
    // fallback atomic accumulators -> zero them.
    hipMemsetAsync(d_out, 0, (size_t)2 * NPIX * sizeof(float), stream);

    // ws ~8 MiB/img (packed f16 cells) -> whole 8-image batch in one chunk
    // (~64 MiB, Infinity-Cache resident together with the out planes).
    int ipc = (int)(ws_size / WS_PER_IMG);
    if (ipc > N_) ipc = N_;

    if (ipc >= 1) {
        unsigned* ws = (unsigned*)d_ws;  // one chunk region, reused
        for (int n0 = 0; n0 < N_; n0 += ipc) {
            int ni = (n0 + ipc <= N_) ? ipc : (N_ - n0);
            splat_tiled_kernel<<<ni * TILES_PER_IMG, 512, 0, stream>>>(
                img, counts, flo, ws, out0, out1, n0);
            int npix_chunk = ni * HW;
            gather_kernel<<<(npix_chunk / 4 + 255) / 256, 256, 0, stream>>>(
                ws, out0, out1, n0, npix_chunk);
        }
    } else {
        const int threads = 256;
        const int blocks = (NPIX + threads - 1) / threads;
        splat_atomic_kernel<<<blocks, threads, 0, stream>>>(img, counts, flo,
                                                            out0, out1);
        finalize_kernel<<<blocks, threads, 0, stream>>>(out0, out1);
    }
}